// Round 1
// baseline (475.262 us; speedup 1.0000x reference)
//
#include <hip/hip_runtime.h>
#include <hip/hip_bf16.h>

typedef __attribute__((ext_vector_type(8))) __bf16 bf16x8;
typedef __attribute__((ext_vector_type(4))) float f32x4;

#define LOG2E 1.4426950408889634f

// ---------------- Kernel 0: transpose + cast weights ----------------
// Wt[p][c][k] = bf16(W_p[k][c]),  p: 0=Q,1=K,2=V.  Wt: [3][128][1024] bf16
__global__ __launch_bounds__(256) void prep_w(const float* __restrict__ Wq,
                                              const float* __restrict__ Wk,
                                              const float* __restrict__ Wv,
                                              __bf16* __restrict__ Wt) {
    int idx = blockIdx.x * 256 + threadIdx.x;   // 3*128*1024 = 393216 total
    int p   = idx >> 17;                        // 131072 per projection
    int rem = idx & 131071;
    int c   = rem >> 10;
    int k   = rem & 1023;
    const float* W = (p == 0) ? Wq : ((p == 1) ? Wk : Wv);
    Wt[idx] = (__bf16)W[k * 128 + c];
}

// ---------------- Kernel 1: fused QKV projection ----------------
// Grid: 256 blocks (64 rows each) x 256 threads (4 waves, 16 rows/wave).
// Each wave computes 16 rows x 384 cols (Q|K|V) via 24 16x16 MFMA tiles.
__global__ __launch_bounds__(256) void qkv_gemm(const float* __restrict__ x,
                                                const __bf16* __restrict__ Wt,
                                                const float* __restrict__ bq,
                                                const float* __restrict__ bk,
                                                const float* __restrict__ bv,
                                                __bf16* __restrict__ qws,
                                                __bf16* __restrict__ kws,
                                                __bf16* __restrict__ vT) {
    const int w  = threadIdx.x >> 6;
    const int l  = threadIdx.x & 63;
    const int lo = l & 15;
    const int hi = l >> 4;
    const int r0 = blockIdx.x * 64 + w * 16;

    const float* xrow = x + (size_t)(r0 + lo) * 1024 + hi * 8;
    const int wt_lane = lo * 1024 + hi * 8;

    f32x4 acc[24];
#pragma unroll
    for (int t = 0; t < 24; ++t) acc[t] = (f32x4){0.f, 0.f, 0.f, 0.f};

    for (int kc = 0; kc < 32; ++kc) {
        const float4* ap = reinterpret_cast<const float4*>(xrow + kc * 32);
        float4 f0 = ap[0];
        float4 f1 = ap[1];
        bf16x8 a;
        a[0] = (__bf16)f0.x; a[1] = (__bf16)f0.y; a[2] = (__bf16)f0.z; a[3] = (__bf16)f0.w;
        a[4] = (__bf16)f1.x; a[5] = (__bf16)f1.y; a[6] = (__bf16)f1.z; a[7] = (__bf16)f1.w;
#pragma unroll
        for (int t = 0; t < 24; ++t) {
            bf16x8 b = *reinterpret_cast<const bf16x8*>(
                Wt + (t >> 3) * 131072 + (t & 7) * 16384 + wt_lane + kc * 32);
            acc[t] = __builtin_amdgcn_mfma_f32_16x16x32_bf16(a, b, acc[t], 0, 0, 0);
        }
    }

    // Epilogue: bias add, Q pre-scaled by 1/sqrt(128), V stored transposed.
#pragma unroll
    for (int t = 0; t < 24; ++t) {
        const int proj = t >> 3;
        const int col  = (t & 7) * 16 + lo;
        const float* bias = (proj == 0) ? bq : ((proj == 1) ? bk : bv);
        const float bb = bias[col];
#pragma unroll
        for (int r = 0; r < 4; ++r) {
            const int row = r0 + hi * 4 + r;
            const float v = acc[t][r] + bb;
            if (proj == 0) {
                qws[(size_t)row * 128 + col] = (__bf16)(v * 0.08838834764831845f);
            } else if (proj == 1) {
                kws[(size_t)row * 128 + col] = (__bf16)v;
            } else {
                const int b_ = row >> 12;
                const int s_ = row & 4095;
                vT[(size_t)b_ * 524288 + (size_t)col * 4096 + s_] = (__bf16)v;
            }
        }
    }
}

// ---------------- Kernel 2: causal flash attention ----------------
// 1 wave per 16-row Q strip. 1024 blocks x 64 threads, longest strips first.
__global__ __launch_bounds__(64) void attn(const __bf16* __restrict__ qws,
                                           const __bf16* __restrict__ kws,
                                           const __bf16* __restrict__ vT,
                                           float* __restrict__ out) {
    __shared__ __align__(16) __bf16 p_lds[16][80];   // padded: stride 160B

    const int l  = threadIdx.x;
    const int lo = l & 15;
    const int hi = l >> 4;

    const int sid   = blockIdx.x;
    const int batch = sid & 3;
    const int m     = 255 - (sid >> 2);   // reversed: longest strips first
    const int r0    = m * 16;
    const int T     = (m >> 2) + 1;       // number of 64-wide KV tiles

    // Q fragments (row = lo, 8 consecutive k per lane-group)
    const size_t qoff = (size_t)(batch * 4096 + r0 + lo) * 128 + hi * 8;
    bf16x8 qf[4];
#pragma unroll
    for (int kc = 0; kc < 4; ++kc)
        qf[kc] = *reinterpret_cast<const bf16x8*>(qws + qoff + kc * 32);

    const __bf16* kb = kws + (size_t)batch * 524288;
    const __bf16* vb = vT  + (size_t)batch * 524288;

    f32x4 o[8];
#pragma unroll
    for (int dt = 0; dt < 8; ++dt) o[dt] = (f32x4){0.f, 0.f, 0.f, 0.f};
    float mr[4], lr[4];
#pragma unroll
    for (int r = 0; r < 4; ++r) { mr[r] = -__builtin_inff(); lr[r] = 0.f; }

    for (int t = 0; t < T; ++t) {
        const int kvb = t * 64;

        // ---- scores S = q . k^T  (16 rows x 64 cols) ----
        f32x4 s[4];
#pragma unroll
        for (int ct = 0; ct < 4; ++ct) s[ct] = (f32x4){0.f, 0.f, 0.f, 0.f};
#pragma unroll
        for (int kc = 0; kc < 4; ++kc) {
#pragma unroll
            for (int ct = 0; ct < 4; ++ct) {
                bf16x8 kf = *reinterpret_cast<const bf16x8*>(
                    kb + (size_t)(kvb + ct * 16 + lo) * 128 + kc * 32 + hi * 8);
                s[ct] = __builtin_amdgcn_mfma_f32_16x16x32_bf16(qf[kc], kf, s[ct], 0, 0, 0);
            }
        }

        // ---- causal mask (only near-diagonal tiles) ----
        if (kvb + 63 > r0) {
#pragma unroll
            for (int ct = 0; ct < 4; ++ct) {
                const int col = kvb + ct * 16 + lo;
#pragma unroll
                for (int r = 0; r < 4; ++r) {
                    const int row = r0 + hi * 4 + r;
                    if (col > row) s[ct][r] = -__builtin_inff();
                }
            }
        }

        // ---- online softmax ----
        float mt[4];
#pragma unroll
        for (int r = 0; r < 4; ++r)
            mt[r] = fmaxf(fmaxf(s[0][r], s[1][r]), fmaxf(s[2][r], s[3][r]));
#pragma unroll
        for (int off = 1; off < 16; off <<= 1) {
#pragma unroll
            for (int r = 0; r < 4; ++r)
                mt[r] = fmaxf(mt[r], __shfl_xor(mt[r], off));
        }

        float alpha[4], rs[4];
#pragma unroll
        for (int r = 0; r < 4; ++r) {
            const float mn = fmaxf(mr[r], mt[r]);
            alpha[r] = exp2f((mr[r] - mn) * LOG2E);
            mr[r] = mn;
            rs[r] = 0.f;
        }
#pragma unroll
        for (int ct = 0; ct < 4; ++ct) {
#pragma unroll
            for (int r = 0; r < 4; ++r) {
                const float p = exp2f((s[ct][r] - mr[r]) * LOG2E);
                s[ct][r] = p;
                rs[r] += p;
            }
        }
#pragma unroll
        for (int off = 1; off < 16; off <<= 1) {
#pragma unroll
            for (int r = 0; r < 4; ++r) rs[r] += __shfl_xor(rs[r], off);
        }
#pragma unroll
        for (int r = 0; r < 4; ++r) lr[r] = lr[r] * alpha[r] + rs[r];
#pragma unroll
        for (int dt = 0; dt < 8; ++dt) {
#pragma unroll
            for (int r = 0; r < 4; ++r) o[dt][r] *= alpha[r];
        }

        // ---- P (C-layout) -> LDS -> A-layout fragments ----
        __syncthreads();
#pragma unroll
        for (int ct = 0; ct < 4; ++ct) {
#pragma unroll
            for (int r = 0; r < 4; ++r)
                p_lds[hi * 4 + r][ct * 16 + lo] = (__bf16)s[ct][r];
        }
        __syncthreads();
        bf16x8 pf0 = *reinterpret_cast<const bf16x8*>(&p_lds[lo][hi * 8]);
        bf16x8 pf1 = *reinterpret_cast<const bf16x8*>(&p_lds[lo][32 + hi * 8]);

        // ---- O += P . V ----
#pragma unroll
        for (int dt = 0; dt < 8; ++dt) {
            bf16x8 vf0 = *reinterpret_cast<const bf16x8*>(
                vb + (size_t)(dt * 16 + lo) * 4096 + kvb + hi * 8);
            o[dt] = __builtin_amdgcn_mfma_f32_16x16x32_bf16(pf0, vf0, o[dt], 0, 0, 0);
            bf16x8 vf1 = *reinterpret_cast<const bf16x8*>(
                vb + (size_t)(dt * 16 + lo) * 4096 + kvb + 32 + hi * 8);
            o[dt] = __builtin_amdgcn_mfma_f32_16x16x32_bf16(pf1, vf1, o[dt], 0, 0, 0);
        }
    }

    // ---- normalize + write f32 output ----
#pragma unroll
    for (int dt = 0; dt < 8; ++dt) {
#pragma unroll
        for (int r = 0; r < 4; ++r) {
            const size_t row = (size_t)(batch * 4096 + r0 + hi * 4 + r);
            out[row * 128 + dt * 16 + lo] = o[dt][r] / lr[r];
        }
    }
}

// ---------------- Launch ----------------
extern "C" void kernel_launch(void* const* d_in, const int* in_sizes, int n_in,
                              void* d_out, int out_size, void* d_ws, size_t ws_size,
                              hipStream_t stream) {
    const float* x  = (const float*)d_in[0];
    const float* Wk = (const float*)d_in[1];
    const float* bk = (const float*)d_in[2];
    const float* Wq = (const float*)d_in[3];
    const float* bq = (const float*)d_in[4];
    const float* Wv = (const float*)d_in[5];
    const float* bv = (const float*)d_in[6];
    float* out = (float*)d_out;

    char* ws = (char*)d_ws;
    __bf16* Wt  = (__bf16*)ws;                                // 786432 B
    __bf16* qws = (__bf16*)(ws + 786432);                     // 4 MB
    __bf16* kws = (__bf16*)(ws + 786432 + 4194304);           // 4 MB
    __bf16* vT  = (__bf16*)(ws + 786432 + 2 * 4194304);       // 4 MB

    prep_w<<<1536, 256, 0, stream>>>(Wq, Wk, Wv, Wt);
    qkv_gemm<<<256, 256, 0, stream>>>(x, Wt, bq, bk, bv, qws, kws, vT);
    attn<<<1024, 64, 0, stream>>>(qws, kws, vT, out);
}

// Round 2
// 361.448 us; speedup vs baseline: 1.3149x; 1.3149x over previous
//
#include <hip/hip_runtime.h>
#include <hip/hip_bf16.h>

typedef __attribute__((ext_vector_type(8))) __bf16 bf16x8;
typedef __attribute__((ext_vector_type(4))) float f32x4;

#define LOG2E 1.4426950408889634f
// 1/sqrt(128) * log2(e): Q pre-scaled so softmax exponents are already base-2
#define QSCALE (0.08838834764831845f * 1.4426950408889634f)

// ---------------- Kernel 0: transpose + cast weights ----------------
// Wt[p][c][k] = bf16(W_p[k][c]),  p: 0=Q,1=K,2=V.  Wt: [3][128][1024] bf16
__global__ __launch_bounds__(256) void prep_w(const float* __restrict__ Wq,
                                              const float* __restrict__ Wk,
                                              const float* __restrict__ Wv,
                                              __bf16* __restrict__ Wt) {
    int idx = blockIdx.x * 256 + threadIdx.x;   // 3*128*1024 = 393216 total
    int p   = idx >> 17;
    int rem = idx & 131071;
    int c   = rem >> 10;
    int k   = rem & 1023;
    const float* W = (p == 0) ? Wq : ((p == 1) ? Wk : Wv);
    Wt[idx] = (__bf16)W[k * 128 + c];
}

// ---------------- Kernel 1: fused QKV projection ----------------
// Grid: 1024 blocks x 256 threads (4 waves). Block owns 16 rows; each wave
// computes 16 rows x 96 cols (6 MFMA col-tiles of the 24 = Q|K|V x 8).
// 4096 waves -> 4 waves/SIMD (was 1).
__global__ __launch_bounds__(256) void qkv_gemm(const float* __restrict__ x,
                                                const __bf16* __restrict__ Wt,
                                                const float* __restrict__ bq,
                                                const float* __restrict__ bk,
                                                const float* __restrict__ bv,
                                                __bf16* __restrict__ qws,
                                                __bf16* __restrict__ kws,
                                                __bf16* __restrict__ vT) {
    const int w  = threadIdx.x >> 6;
    const int l  = threadIdx.x & 63;
    const int lo = l & 15;
    const int hi = l >> 4;
    const int r0 = blockIdx.x * 16;

    const float* xrow = x + (size_t)(r0 + lo) * 1024 + hi * 8;
    const int wt_lane = lo * 1024 + hi * 8;

    f32x4 acc[6];
#pragma unroll
    for (int t = 0; t < 6; ++t) acc[t] = (f32x4){0.f, 0.f, 0.f, 0.f};

    for (int kc = 0; kc < 32; ++kc) {
        const float4* ap = reinterpret_cast<const float4*>(xrow + kc * 32);
        float4 f0 = ap[0];
        float4 f1 = ap[1];
        bf16x8 a;
        a[0] = (__bf16)f0.x; a[1] = (__bf16)f0.y; a[2] = (__bf16)f0.z; a[3] = (__bf16)f0.w;
        a[4] = (__bf16)f1.x; a[5] = (__bf16)f1.y; a[6] = (__bf16)f1.z; a[7] = (__bf16)f1.w;
#pragma unroll
        for (int tt = 0; tt < 6; ++tt) {
            const int t = w * 6 + tt;
            bf16x8 b = *reinterpret_cast<const bf16x8*>(
                Wt + (t >> 3) * 131072 + (t & 7) * 16384 + wt_lane + kc * 32);
            acc[tt] = __builtin_amdgcn_mfma_f32_16x16x32_bf16(a, b, acc[tt], 0, 0, 0);
        }
    }

    // Epilogue: bias add; Q pre-scaled by (1/sqrt(128))*log2(e); V transposed.
#pragma unroll
    for (int tt = 0; tt < 6; ++tt) {
        const int t    = w * 6 + tt;
        const int proj = t >> 3;
        const int col  = (t & 7) * 16 + lo;
        const float* bias = (proj == 0) ? bq : ((proj == 1) ? bk : bv);
        const float bb = bias[col];
#pragma unroll
        for (int r = 0; r < 4; ++r) {
            const int row = r0 + hi * 4 + r;
            const float v = acc[tt][r] + bb;
            if (proj == 0) {
                qws[(size_t)row * 128 + col] = (__bf16)(v * QSCALE);
            } else if (proj == 1) {
                kws[(size_t)row * 128 + col] = (__bf16)v;
            } else {
                const int b_ = row >> 12;
                const int s_ = row & 4095;
                vT[(size_t)b_ * 524288 + (size_t)col * 4096 + s_] = (__bf16)v;
            }
        }
    }
}

// ---------------- Kernel 2: causal flash attention (KV-split) ----------------
// 1 wave per (16-row Q strip, KV segment). Writes unnormalized partial
// (O[16][128], m[16], l[16]) per task; combine kernel reduces over segments.
// Slot layout: 2080 floats = [16][128] O, [16] m, [16] l.
__global__ __launch_bounds__(64) void attn(const __bf16* __restrict__ qws,
                                           const __bf16* __restrict__ kws,
                                           const __bf16* __restrict__ vT,
                                           float* __restrict__ part,
                                           float* __restrict__ out,
                                           int NSEG, int SEG, int direct) {
    __shared__ __align__(16) __bf16 p_lds[16][80];   // padded: stride 160B

    const int l  = threadIdx.x;
    const int lo = l & 15;
    const int hi = l >> 4;

    const int bid   = blockIdx.x;
    const int strip = bid / NSEG;
    const int seg   = bid - strip * NSEG;
    const int batch = strip & 3;
    const int m     = 255 - (strip >> 2);   // reversed: longest strips first
    const int r0    = m * 16;
    const int limit = r0 + 16;              // causal KV extent for this strip

    const int kv_start = seg * SEG;
    if (kv_start >= limit) return;          // empty segment
    const int kv_end = min(kv_start + SEG, limit);
    const int t0 = kv_start >> 6;
    const int t1 = (kv_end + 63) >> 6;

    // Q fragments (row = lo, 8 consecutive k per lane-group)
    const size_t qoff = (size_t)(batch * 4096 + r0 + lo) * 128 + hi * 8;
    bf16x8 qf[4];
#pragma unroll
    for (int kc = 0; kc < 4; ++kc)
        qf[kc] = *reinterpret_cast<const bf16x8*>(qws + qoff + kc * 32);

    const __bf16* kb = kws + (size_t)batch * 524288;
    const __bf16* vb = vT  + (size_t)batch * 524288;

    f32x4 o[8];
#pragma unroll
    for (int dt = 0; dt < 8; ++dt) o[dt] = (f32x4){0.f, 0.f, 0.f, 0.f};
    float mr[4], lr[4];
#pragma unroll
    for (int r = 0; r < 4; ++r) { mr[r] = -__builtin_inff(); lr[r] = 0.f; }

    for (int t = t0; t < t1; ++t) {
        const int kvb = t * 64;

        // ---- scores S = q . k^T  (16 rows x 64 cols), already log2-scaled ----
        f32x4 s[4];
#pragma unroll
        for (int ct = 0; ct < 4; ++ct) s[ct] = (f32x4){0.f, 0.f, 0.f, 0.f};
#pragma unroll
        for (int kc = 0; kc < 4; ++kc) {
#pragma unroll
            for (int ct = 0; ct < 4; ++ct) {
                bf16x8 kf = *reinterpret_cast<const bf16x8*>(
                    kb + (size_t)(kvb + ct * 16 + lo) * 128 + kc * 32 + hi * 8);
                s[ct] = __builtin_amdgcn_mfma_f32_16x16x32_bf16(qf[kc], kf, s[ct], 0, 0, 0);
            }
        }

        // ---- issue V loads early: they fly under the softmax VALU work ----
        bf16x8 vf[8];
#pragma unroll
        for (int dt = 0; dt < 8; ++dt)
            vf[dt] = *reinterpret_cast<const bf16x8*>(
                vb + (size_t)(dt * 16 + lo) * 4096 + kvb + hi * 8);

        // ---- causal mask (only near-diagonal tiles) ----
        if (kvb + 63 > r0) {
#pragma unroll
            for (int ct = 0; ct < 4; ++ct) {
                const int col = kvb + ct * 16 + lo;
#pragma unroll
                for (int r = 0; r < 4; ++r) {
                    const int row = r0 + hi * 4 + r;
                    if (col > row) s[ct][r] = -__builtin_inff();
                }
            }
        }

        // ---- online softmax (base-2 exponents) ----
        float mt[4];
#pragma unroll
        for (int r = 0; r < 4; ++r)
            mt[r] = fmaxf(fmaxf(s[0][r], s[1][r]), fmaxf(s[2][r], s[3][r]));
#pragma unroll
        for (int off = 1; off < 16; off <<= 1) {
#pragma unroll
            for (int r = 0; r < 4; ++r)
                mt[r] = fmaxf(mt[r], __shfl_xor(mt[r], off));
        }

        float alpha[4], rs[4];
#pragma unroll
        for (int r = 0; r < 4; ++r) {
            const float mn = fmaxf(mr[r], mt[r]);
            alpha[r] = exp2f(mr[r] - mn);
            mr[r] = mn;
            rs[r] = 0.f;
        }
#pragma unroll
        for (int ct = 0; ct < 4; ++ct) {
#pragma unroll
            for (int r = 0; r < 4; ++r) {
                const float p = exp2f(s[ct][r] - mr[r]);
                s[ct][r] = p;
                rs[r] += p;
            }
        }
#pragma unroll
        for (int off = 1; off < 16; off <<= 1) {
#pragma unroll
            for (int r = 0; r < 4; ++r) rs[r] += __shfl_xor(rs[r], off);
        }
#pragma unroll
        for (int r = 0; r < 4; ++r) lr[r] = lr[r] * alpha[r] + rs[r];
#pragma unroll
        for (int dt = 0; dt < 8; ++dt) {
#pragma unroll
            for (int r = 0; r < 4; ++r) o[dt][r] *= alpha[r];
        }

        // ---- P (C-layout) -> LDS -> A-layout fragments ----
        __syncthreads();
#pragma unroll
        for (int ct = 0; ct < 4; ++ct) {
#pragma unroll
            for (int r = 0; r < 4; ++r)
                p_lds[hi * 4 + r][ct * 16 + lo] = (__bf16)s[ct][r];
        }
        __syncthreads();
        bf16x8 pf0 = *reinterpret_cast<const bf16x8*>(&p_lds[lo][hi * 8]);
        bf16x8 pf1 = *reinterpret_cast<const bf16x8*>(&p_lds[lo][32 + hi * 8]);

        // ---- O += P . V ----
#pragma unroll
        for (int dt = 0; dt < 8; ++dt) {
            o[dt] = __builtin_amdgcn_mfma_f32_16x16x32_bf16(pf0, vf[dt], o[dt], 0, 0, 0);
            bf16x8 vf1 = *reinterpret_cast<const bf16x8*>(
                vb + (size_t)(dt * 16 + lo) * 4096 + kvb + 32 + hi * 8);
            o[dt] = __builtin_amdgcn_mfma_f32_16x16x32_bf16(pf1, vf1, o[dt], 0, 0, 0);
        }
    }

    if (direct) {
        // single-segment fallback: normalize and write final output
#pragma unroll
        for (int dt = 0; dt < 8; ++dt) {
#pragma unroll
            for (int r = 0; r < 4; ++r) {
                const size_t row = (size_t)(batch * 4096 + r0 + hi * 4 + r);
                out[row * 128 + dt * 16 + lo] = o[dt][r] / lr[r];
            }
        }
    } else {
        float* slot = part + ((size_t)strip * NSEG + seg) * 2080;
#pragma unroll
        for (int dt = 0; dt < 8; ++dt) {
#pragma unroll
            for (int r = 0; r < 4; ++r)
                slot[(hi * 4 + r) * 128 + dt * 16 + lo] = o[dt][r];
        }
        if (lo == 0) {
#pragma unroll
            for (int r = 0; r < 4; ++r) {
                slot[2048 + hi * 4 + r] = mr[r];
                slot[2064 + hi * 4 + r] = lr[r];
            }
        }
    }
}

// ---------------- Kernel 3: combine KV-split partials ----------------
// 1024 blocks (one per strip) x 256 threads. Thread: row = tid>>4,
// cols [(tid&15)*8, +8).
__global__ __launch_bounds__(256) void combine(const float* __restrict__ part,
                                               float* __restrict__ out,
                                               int NSEG, int SEG) {
    const int strip = blockIdx.x;
    const int batch = strip & 3;
    const int m     = 255 - (strip >> 2);
    const int limit = m * 16 + 16;
    const int nseg  = (limit + SEG - 1) / SEG;

    const int r  = threadIdx.x >> 4;
    const int c0 = (threadIdx.x & 15) * 8;
    const float* base = part + (size_t)strip * NSEG * 2080;

    float mj[8], wj[8];
    float M = -__builtin_inff();
#pragma unroll 8
    for (int j = 0; j < 8; ++j) {
        if (j < nseg) {
            mj[j] = base[j * 2080 + 2048 + r];
            M = fmaxf(M, mj[j]);
        }
    }
    float L = 0.f;
#pragma unroll 8
    for (int j = 0; j < 8; ++j) {
        if (j < nseg) {
            wj[j] = exp2f(mj[j] - M);
            L += base[j * 2080 + 2064 + r] * wj[j];
        }
    }

    float a0=0,a1=0,a2=0,a3=0,a4=0,a5=0,a6=0,a7=0;
#pragma unroll 8
    for (int j = 0; j < 8; ++j) {
        if (j < nseg) {
            const float4* p4 = reinterpret_cast<const float4*>(base + j * 2080 + r * 128 + c0);
            float4 x = p4[0], y = p4[1];
            const float w = wj[j];
            a0 += x.x*w; a1 += x.y*w; a2 += x.z*w; a3 += x.w*w;
            a4 += y.x*w; a5 += y.y*w; a6 += y.z*w; a7 += y.w*w;
        }
    }
    const float inv = 1.f / L;
    float* op = out + ((size_t)(batch * 4096 + m * 16 + r)) * 128 + c0;
    float4* o4 = reinterpret_cast<float4*>(op);
    o4[0] = (float4){a0*inv, a1*inv, a2*inv, a3*inv};
    o4[1] = (float4){a4*inv, a5*inv, a6*inv, a7*inv};
}

// ---------------- Launch ----------------
extern "C" void kernel_launch(void* const* d_in, const int* in_sizes, int n_in,
                              void* d_out, int out_size, void* d_ws, size_t ws_size,
                              hipStream_t stream) {
    const float* x  = (const float*)d_in[0];
    const float* Wk = (const float*)d_in[1];
    const float* bk = (const float*)d_in[2];
    const float* Wq = (const float*)d_in[3];
    const float* bq = (const float*)d_in[4];
    const float* Wv = (const float*)d_in[5];
    const float* bv = (const float*)d_in[6];
    float* out = (float*)d_out;

    char* ws = (char*)d_ws;
    __bf16* Wt  = (__bf16*)ws;                                // 786432 B
    __bf16* qws = (__bf16*)(ws + 786432);                     // 4 MB
    __bf16* kws = (__bf16*)(ws + 786432 + 4194304);           // 4 MB
    __bf16* vT  = (__bf16*)(ws + 786432 + 2 * 4194304);       // 4 MB
    const size_t base = 786432 + 3 * 4194304;                 // 13369344 B

    // pick the largest KV-split that fits in the workspace
    const size_t per_seg = 1024ull * 2080 * 4;                // bytes per NSEG unit
    int NSEG = 0;
    for (int cand = 8; cand >= 1; cand >>= 1) {
        if (base + (size_t)cand * per_seg <= ws_size) { NSEG = cand; break; }
    }
    float* part = (float*)(ws + base);

    prep_w<<<1536, 256, 0, stream>>>(Wq, Wk, Wv, Wt);
    qkv_gemm<<<1024, 256, 0, stream>>>(x, Wt, bq, bk, bv, qws, kws, vT);

    if (NSEG >= 1) {
        const int SEG = 4096 / NSEG;
        attn<<<1024 * NSEG, 64, 0, stream>>>(qws, kws, vT, part, out, NSEG, SEG, 0);
        combine<<<1024, 256, 0, stream>>>(part, out, NSEG, SEG);
    } else {
        attn<<<1024, 64, 0, stream>>>(qws, kws, vT, nullptr, out, 1, 4096, 1);
    }
}

// Round 3
// 272.265 us; speedup vs baseline: 1.7456x; 1.3276x over previous
//
#include <hip/hip_runtime.h>
#include <hip/hip_bf16.h>

typedef __attribute__((ext_vector_type(8))) __bf16 bf16x8;
typedef __attribute__((ext_vector_type(4))) float f32x4;

// 1/sqrt(128) * log2(e): Q pre-scaled so softmax exponents are base-2
#define QSCALE (0.08838834764831845f * 1.4426950408889634f)

// ---------------- Kernel 0: transpose + cast weights ----------------
__global__ __launch_bounds__(256) void prep_w(const float* __restrict__ Wq,
                                              const float* __restrict__ Wk,
                                              const float* __restrict__ Wv,
                                              __bf16* __restrict__ Wt) {
    int idx = blockIdx.x * 256 + threadIdx.x;   // 3*128*1024 total
    int p   = idx >> 17;
    int rem = idx & 131071;
    int c   = rem >> 10;
    int k   = rem & 1023;
    const float* W = (p == 0) ? Wq : ((p == 1) ? Wk : Wv);
    Wt[idx] = (__bf16)W[k * 128 + c];
}

// ---------------- Kernel 1: fused QKV projection ----------------
__global__ __launch_bounds__(256) void qkv_gemm(const float* __restrict__ x,
                                                const __bf16* __restrict__ Wt,
                                                const float* __restrict__ bq,
                                                const float* __restrict__ bk,
                                                const float* __restrict__ bv,
                                                __bf16* __restrict__ qws,
                                                __bf16* __restrict__ kws,
                                                __bf16* __restrict__ vT) {
    const int w  = threadIdx.x >> 6;
    const int l  = threadIdx.x & 63;
    const int lo = l & 15;
    const int hi = l >> 4;
    const int r0 = blockIdx.x * 16;

    const float* xrow = x + (size_t)(r0 + lo) * 1024 + hi * 8;
    const int wt_lane = lo * 1024 + hi * 8;

    f32x4 acc[6];
#pragma unroll
    for (int t = 0; t < 6; ++t) acc[t] = (f32x4){0.f, 0.f, 0.f, 0.f};

#pragma unroll 4
    for (int kc = 0; kc < 32; ++kc) {
        const float4* ap = reinterpret_cast<const float4*>(xrow + kc * 32);
        float4 f0 = ap[0];
        float4 f1 = ap[1];
        bf16x8 a;
        a[0] = (__bf16)f0.x; a[1] = (__bf16)f0.y; a[2] = (__bf16)f0.z; a[3] = (__bf16)f0.w;
        a[4] = (__bf16)f1.x; a[5] = (__bf16)f1.y; a[6] = (__bf16)f1.z; a[7] = (__bf16)f1.w;
#pragma unroll
        for (int tt = 0; tt < 6; ++tt) {
            const int t = w * 6 + tt;
            bf16x8 b = *reinterpret_cast<const bf16x8*>(
                Wt + (t >> 3) * 131072 + (t & 7) * 16384 + wt_lane + kc * 32);
            acc[tt] = __builtin_amdgcn_mfma_f32_16x16x32_bf16(a, b, acc[tt], 0, 0, 0);
        }
    }

#pragma unroll
    for (int tt = 0; tt < 6; ++tt) {
        const int t    = w * 6 + tt;
        const int proj = t >> 3;
        const int col  = (t & 7) * 16 + lo;
        const float* bias = (proj == 0) ? bq : ((proj == 1) ? bk : bv);
        const float bb = bias[col];
#pragma unroll
        for (int r = 0; r < 4; ++r) {
            const int row = r0 + hi * 4 + r;
            const float v = acc[tt][r] + bb;
            if (proj == 0) {
                qws[(size_t)row * 128 + col] = (__bf16)(v * QSCALE);
            } else if (proj == 1) {
                kws[(size_t)row * 128 + col] = (__bf16)v;
            } else {
                const int b_ = row >> 12;
                const int s_ = row & 4095;
                vT[(size_t)b_ * 524288 + (size_t)col * 4096 + s_] = (__bf16)v;
            }
        }
    }
}

// ---------------- Kernel 2: causal flash attention ----------------
// 4 waves/block, 64 Q rows/block (wave w owns rows [r0+16w, +16)).
// K tile [64][128] double-buffered in LDS, XOR-swizzled (unit ^= row&7) via
// pre-swizzled global source; reg-staged (load early / ds_write late).
// KV-split over NSEG segments -> partials (O,m,l), combined by kernel 3.
// Partial slot: 8320 floats = [64][128] O + [64] m + [64] l.
__global__ __launch_bounds__(256) void attn(const __bf16* __restrict__ qws,
                                            const __bf16* __restrict__ kws,
                                            const __bf16* __restrict__ vT,
                                            float* __restrict__ part,
                                            float* __restrict__ out,
                                            int NSEG, int SEG, int direct) {
    __shared__ __align__(16) __bf16 kbuf[2][64 * 128];   // 2 x 16 KB
    __shared__ __align__(16) __bf16 p_lds[4][16][80];    // wave-private P

    const int tid = threadIdx.x;
    const int w   = tid >> 6;
    const int l   = tid & 63;
    const int lo  = l & 15;
    const int hi  = l >> 4;

    const int bid   = blockIdx.x;
    const int strip = bid / NSEG;          // 0..255
    const int seg   = bid - strip * NSEG;
    const int batch = strip & 3;
    const int mblk  = 63 - (strip >> 2);   // longest strips first
    const int r0    = mblk * 64;
    const int limit = r0 + 64;             // causal KV extent (64-aligned)

    const int kv_start = seg * SEG;
    if (kv_start >= limit) return;
    const int kv_end = min(kv_start + SEG, limit);
    const int t0 = kv_start >> 6;
    const int t1 = (kv_end + 63) >> 6;

    const int rw = r0 + w * 16;            // this wave's first q row

    // Q fragments
    const size_t qoff = (size_t)(batch * 4096 + rw + lo) * 128 + hi * 8;
    bf16x8 qf[4];
#pragma unroll
    for (int kc = 0; kc < 4; ++kc)
        qf[kc] = *reinterpret_cast<const bf16x8*>(qws + qoff + kc * 32);

    const __bf16* kb = kws + (size_t)batch * 524288;
    const __bf16* vb = vT  + (size_t)batch * 524288;

    // ---- prologue: stage K tile t0 into kbuf[0] ----
    {
        const int kvb = t0 * 64;
        bf16x8 kr[4];
#pragma unroll
        for (int i = 0; i < 4; ++i) {
            const int row = w * 16 + i * 4 + hi;
            kr[i] = *reinterpret_cast<const bf16x8*>(
                kb + (size_t)(kvb + row) * 128 + ((lo ^ (row & 7)) << 3));
        }
#pragma unroll
        for (int i = 0; i < 4; ++i)
            *reinterpret_cast<bf16x8*>(&kbuf[0][(w * 16 + i * 4 + hi) * 128 + lo * 8]) = kr[i];
        __syncthreads();
    }
    int cur = 0;

    f32x4 o[8];
#pragma unroll
    for (int dt = 0; dt < 8; ++dt) o[dt] = (f32x4){0.f, 0.f, 0.f, 0.f};
    float mr[4], lr[4];
#pragma unroll
    for (int r = 0; r < 4; ++r) { mr[r] = -__builtin_inff(); lr[r] = 0.f; }

    for (int t = t0; t < t1; ++t) {
        const int kvb = t * 64;
        const int nxt = cur ^ 1;
        const bool pfetch = (t + 1 < t1);

        // ---- issue next K tile's global loads (fly under compute) ----
        bf16x8 kr[4];
        if (pfetch) {
            const int kvn = kvb + 64;
#pragma unroll
            for (int i = 0; i < 4; ++i) {
                const int row = w * 16 + i * 4 + hi;
                kr[i] = *reinterpret_cast<const bf16x8*>(
                    kb + (size_t)(kvn + row) * 128 + ((lo ^ (row & 7)) << 3));
            }
        }

        // ---- S = q . k^T from LDS (swizzled reads, conflict-free) ----
        f32x4 s[4];
#pragma unroll
        for (int ct = 0; ct < 4; ++ct) s[ct] = (f32x4){0.f, 0.f, 0.f, 0.f};
#pragma unroll
        for (int kc = 0; kc < 4; ++kc) {
#pragma unroll
            for (int ct = 0; ct < 4; ++ct) {
                const int row = ct * 16 + lo;
                bf16x8 kf = *reinterpret_cast<const bf16x8*>(
                    &kbuf[cur][row * 128 + (((kc * 4 + hi) ^ (lo & 7)) << 3)]);
                s[ct] = __builtin_amdgcn_mfma_f32_16x16x32_bf16(qf[kc], kf, s[ct], 0, 0, 0);
            }
        }

        // ---- V loads issued early (under softmax VALU) ----
        bf16x8 vf[8];
#pragma unroll
        for (int dt = 0; dt < 8; ++dt)
            vf[dt] = *reinterpret_cast<const bf16x8*>(
                vb + (size_t)(dt * 16 + lo) * 4096 + kvb + hi * 8);

        // ---- causal mask: only the diagonal tile (kvb == r0) ----
        if (kvb + 63 > rw) {
#pragma unroll
            for (int ct = 0; ct < 4; ++ct) {
                const int col = kvb + ct * 16 + lo;
#pragma unroll
                for (int r = 0; r < 4; ++r) {
                    const int row = rw + hi * 4 + r;
                    if (col > row) s[ct][r] = -__builtin_inff();
                }
            }
        }

        // ---- online softmax (base-2) ----
        float mt[4];
#pragma unroll
        for (int r = 0; r < 4; ++r)
            mt[r] = fmaxf(fmaxf(s[0][r], s[1][r]), fmaxf(s[2][r], s[3][r]));
#pragma unroll
        for (int off = 1; off < 16; off <<= 1) {
#pragma unroll
            for (int r = 0; r < 4; ++r)
                mt[r] = fmaxf(mt[r], __shfl_xor(mt[r], off));
        }

        float alpha[4], rs[4];
#pragma unroll
        for (int r = 0; r < 4; ++r) {
            const float mn = fmaxf(mr[r], mt[r]);
            alpha[r] = exp2f(mr[r] - mn);
            mr[r] = mn;
            rs[r] = 0.f;
        }
#pragma unroll
        for (int ct = 0; ct < 4; ++ct) {
#pragma unroll
            for (int r = 0; r < 4; ++r) {
                const float p = exp2f(s[ct][r] - mr[r]);
                s[ct][r] = p;
                rs[r] += p;
            }
        }
#pragma unroll
        for (int off = 1; off < 16; off <<= 1) {
#pragma unroll
            for (int r = 0; r < 4; ++r) rs[r] += __shfl_xor(rs[r], off);
        }
#pragma unroll
        for (int r = 0; r < 4; ++r) lr[r] = lr[r] * alpha[r] + rs[r];
#pragma unroll
        for (int dt = 0; dt < 8; ++dt) {
#pragma unroll
            for (int r = 0; r < 4; ++r) o[dt][r] *= alpha[r];
        }

        // ---- P (C-layout) -> wave-private LDS -> A-layout fragments ----
#pragma unroll
        for (int ct = 0; ct < 4; ++ct) {
#pragma unroll
            for (int r = 0; r < 4; ++r)
                p_lds[w][hi * 4 + r][ct * 16 + lo] = (__bf16)s[ct][r];
        }
        bf16x8 pf0 = *reinterpret_cast<const bf16x8*>(&p_lds[w][lo][hi * 8]);
        bf16x8 pf1 = *reinterpret_cast<const bf16x8*>(&p_lds[w][lo][32 + hi * 8]);

        // ---- O += P . V ----
#pragma unroll
        for (int dt = 0; dt < 8; ++dt) {
            o[dt] = __builtin_amdgcn_mfma_f32_16x16x32_bf16(pf0, vf[dt], o[dt], 0, 0, 0);
            bf16x8 vf1 = *reinterpret_cast<const bf16x8*>(
                vb + (size_t)(dt * 16 + lo) * 4096 + kvb + 32 + hi * 8);
            o[dt] = __builtin_amdgcn_mfma_f32_16x16x32_bf16(pf1, vf1, o[dt], 0, 0, 0);
        }

        // ---- write staged K regs into the other buffer, flip ----
        if (pfetch) {
#pragma unroll
            for (int i = 0; i < 4; ++i)
                *reinterpret_cast<bf16x8*>(
                    &kbuf[nxt][(w * 16 + i * 4 + hi) * 128 + lo * 8]) = kr[i];
        }
        __syncthreads();
        cur = nxt;
    }

    if (direct) {
#pragma unroll
        for (int dt = 0; dt < 8; ++dt) {
#pragma unroll
            for (int r = 0; r < 4; ++r) {
                const size_t row = (size_t)(batch * 4096 + rw + hi * 4 + r);
                out[row * 128 + dt * 16 + lo] = o[dt][r] / lr[r];
            }
        }
    } else {
        float* slot = part + ((size_t)strip * NSEG + seg) * 8320;
#pragma unroll
        for (int dt = 0; dt < 8; ++dt) {
#pragma unroll
            for (int r = 0; r < 4; ++r)
                slot[(w * 16 + hi * 4 + r) * 128 + dt * 16 + lo] = o[dt][r];
        }
        if (lo == 0) {
#pragma unroll
            for (int r = 0; r < 4; ++r) {
                slot[8192 + w * 16 + hi * 4 + r] = mr[r];
                slot[8256 + w * 16 + hi * 4 + r] = lr[r];
            }
        }
    }
}

// ---------------- Kernel 3: combine KV-split partials ----------------
// 1024 blocks x 256 thr; block handles 16 rows of one strip.
__global__ __launch_bounds__(256) void combine(const float* __restrict__ part,
                                               float* __restrict__ out,
                                               int NSEG, int SEG) {
    const int strip = blockIdx.x >> 2;
    const int rg    = blockIdx.x & 3;
    const int batch = strip & 3;
    const int mblk  = 63 - (strip >> 2);
    const int limit = mblk * 64 + 64;
    const int nseg  = min(NSEG, (limit + SEG - 1) / SEG);

    const int rl = rg * 16 + (threadIdx.x >> 4);   // 0..63 row within strip
    const int c0 = (threadIdx.x & 15) * 8;
    const float* base = part + (size_t)strip * NSEG * 8320;

    float mj[8];
    float M = -__builtin_inff();
#pragma unroll 8
    for (int j = 0; j < 8; ++j) {
        if (j < nseg) {
            mj[j] = base[j * 8320 + 8192 + rl];
            M = fmaxf(M, mj[j]);
        }
    }
    float wj[8];
    float L = 0.f;
#pragma unroll 8
    for (int j = 0; j < 8; ++j) {
        if (j < nseg) {
            wj[j] = exp2f(mj[j] - M);
            L += base[j * 8320 + 8256 + rl] * wj[j];
        }
    }

    float a0=0,a1=0,a2=0,a3=0,a4=0,a5=0,a6=0,a7=0;
#pragma unroll 8
    for (int j = 0; j < 8; ++j) {
        if (j < nseg) {
            const float4* p4 = reinterpret_cast<const float4*>(base + j * 8320 + rl * 128 + c0);
            float4 x = p4[0], y = p4[1];
            const float wgt = wj[j];
            a0 += x.x*wgt; a1 += x.y*wgt; a2 += x.z*wgt; a3 += x.w*wgt;
            a4 += y.x*wgt; a5 += y.y*wgt; a6 += y.z*wgt; a7 += y.w*wgt;
        }
    }
    const float inv = 1.f / L;
    float* op = out + ((size_t)(batch * 4096 + mblk * 64 + rl)) * 128 + c0;
    float4* o4 = reinterpret_cast<float4*>(op);
    o4[0] = (float4){a0*inv, a1*inv, a2*inv, a3*inv};
    o4[1] = (float4){a4*inv, a5*inv, a6*inv, a7*inv};
}

// ---------------- Launch ----------------
extern "C" void kernel_launch(void* const* d_in, const int* in_sizes, int n_in,
                              void* d_out, int out_size, void* d_ws, size_t ws_size,
                              hipStream_t stream) {
    const float* x  = (const float*)d_in[0];
    const float* Wk = (const float*)d_in[1];
    const float* bk = (const float*)d_in[2];
    const float* Wq = (const float*)d_in[3];
    const float* bq = (const float*)d_in[4];
    const float* Wv = (const float*)d_in[5];
    const float* bv = (const float*)d_in[6];
    float* out = (float*)d_out;

    char* ws = (char*)d_ws;
    __bf16* Wt  = (__bf16*)ws;                                // 786432 B
    __bf16* qws = (__bf16*)(ws + 786432);                     // 4 MB
    __bf16* kws = (__bf16*)(ws + 786432 + 4194304);           // 4 MB
    __bf16* vT  = (__bf16*)(ws + 786432 + 2 * 4194304);       // 4 MB
    const size_t base = 786432 + 3 * 4194304;                 // 13369344 B

    // largest KV-split that fits: per NSEG unit = 256 strips * 8320 * 4 B
    const size_t per_seg = 256ull * 8320 * 4;
    int NSEG = 0;
    for (int cand = 8; cand >= 1; cand >>= 1) {
        if (base + (size_t)cand * per_seg <= ws_size) { NSEG = cand; break; }
    }
    float* part = (float*)(ws + base);

    prep_w<<<1536, 256, 0, stream>>>(Wq, Wk, Wv, Wt);
    qkv_gemm<<<1024, 256, 0, stream>>>(x, Wt, bq, bk, bv, qws, kws, vT);

    if (NSEG >= 2) {
        const int SEG = 4096 / NSEG;
        attn<<<256 * NSEG, 256, 0, stream>>>(qws, kws, vT, part, out, NSEG, SEG, 0);
        combine<<<1024, 256, 0, stream>>>(part, out, NSEG, SEG);
    } else {
        attn<<<256, 256, 0, stream>>>(qws, kws, vT, nullptr, out, 1, 4096, 1);
    }
}

// Round 4
// 265.804 us; speedup vs baseline: 1.7880x; 1.0243x over previous
//
#include <hip/hip_runtime.h>
#include <hip/hip_bf16.h>

typedef __attribute__((ext_vector_type(8))) __bf16 bf16x8;
typedef __attribute__((ext_vector_type(4))) float f32x4;

// 1/sqrt(128) * log2(e): Q pre-scaled so softmax exponents are base-2
#define QSCALE (0.08838834764831845f * 1.4426950408889634f)

static __device__ __forceinline__ int pack2(float a, float b) {
    union { __bf16 h[2]; int u; } x;
    x.h[0] = (__bf16)a; x.h[1] = (__bf16)b;
    return x.u;
}

// ---------------- Kernel 0: transpose + cast weights ----------------
// Wt[p][c][k] = bf16(W_p[k][c]),  p: 0=Q,1=K,2=V.  Wt: [3][128][1024] bf16
__global__ __launch_bounds__(256) void prep_w(const float* __restrict__ Wq,
                                              const float* __restrict__ Wk,
                                              const float* __restrict__ Wv,
                                              __bf16* __restrict__ Wt) {
    int idx = blockIdx.x * 256 + threadIdx.x;
    int p   = idx >> 17;
    int rem = idx & 131071;
    int c   = rem >> 10;
    int k   = rem & 1023;
    const float* W = (p == 0) ? Wq : ((p == 1) ? Wk : Wv);
    Wt[idx] = (__bf16)W[k * 128 + c];
}

// ---------------- Kernel 1: fused QKV projection ----------------
// 512 blocks x 512 thr (8 waves). Block stages x[32][1024] -> LDS bf16
// (XOR-swizzled 16B units). Wave w: col-tiles w*3..w*3+2, both 16-row tiles.
__global__ __launch_bounds__(512) void qkv_gemm(const float* __restrict__ x,
                                                const __bf16* __restrict__ Wt,
                                                const float* __restrict__ bq,
                                                const float* __restrict__ bk,
                                                const float* __restrict__ bv,
                                                __bf16* __restrict__ qws,
                                                __bf16* __restrict__ kws,
                                                __bf16* __restrict__ vT) {
    __shared__ __align__(16) __bf16 xb[32 * 1024];   // 64 KB

    const int tid = threadIdx.x;
    const int w   = tid >> 6;
    const int l   = tid & 63;
    const int lo  = l & 15;
    const int hi  = l >> 4;
    const int r0  = blockIdx.x * 32;

    // ---- stage x tile (f32 -> bf16, swizzled) ----
#pragma unroll
    for (int i = 0; i < 8; ++i) {
        const int ul  = i * 512 + tid;      // 0..4095 16B-units
        const int row = ul >> 7;            // 0..31
        const int u   = ul & 127;
        const float4* src = reinterpret_cast<const float4*>(
            x + (size_t)(r0 + row) * 1024 + u * 8);
        float4 f0 = src[0], f1 = src[1];
        bf16x8 v;
        v[0]=(__bf16)f0.x; v[1]=(__bf16)f0.y; v[2]=(__bf16)f0.z; v[3]=(__bf16)f0.w;
        v[4]=(__bf16)f1.x; v[5]=(__bf16)f1.y; v[6]=(__bf16)f1.z; v[7]=(__bf16)f1.w;
        *reinterpret_cast<bf16x8*>(&xb[row * 1024 + ((u ^ (row & 7)) * 8)]) = v;
    }
    __syncthreads();

    f32x4 acc[2][3];
#pragma unroll
    for (int rt = 0; rt < 2; ++rt)
#pragma unroll
        for (int tt = 0; tt < 3; ++tt) acc[rt][tt] = (f32x4){0.f, 0.f, 0.f, 0.f};

    const int tbase = w * 3;
#pragma unroll 4
    for (int kc = 0; kc < 32; ++kc) {
        const int usw = ((kc * 4 + hi) ^ (lo & 7)) * 8;
        bf16x8 a0 = *reinterpret_cast<const bf16x8*>(&xb[lo * 1024 + usw]);
        bf16x8 a1 = *reinterpret_cast<const bf16x8*>(&xb[(16 + lo) * 1024 + usw]);
#pragma unroll
        for (int tt = 0; tt < 3; ++tt) {
            const int t = tbase + tt;
            bf16x8 b = *reinterpret_cast<const bf16x8*>(
                Wt + (t >> 3) * 131072 + (t & 7) * 16384 + lo * 1024 + kc * 32 + hi * 8);
            acc[0][tt] = __builtin_amdgcn_mfma_f32_16x16x32_bf16(a0, b, acc[0][tt], 0, 0, 0);
            acc[1][tt] = __builtin_amdgcn_mfma_f32_16x16x32_bf16(a1, b, acc[1][tt], 0, 0, 0);
        }
    }

#pragma unroll
    for (int tt = 0; tt < 3; ++tt) {
        const int t    = tbase + tt;
        const int proj = t >> 3;
        const int col  = (t & 7) * 16 + lo;
        const float* bias = (proj == 0) ? bq : ((proj == 1) ? bk : bv);
        const float bb = bias[col];
#pragma unroll
        for (int rt = 0; rt < 2; ++rt) {
#pragma unroll
            for (int r = 0; r < 4; ++r) {
                const int row = r0 + rt * 16 + hi * 4 + r;
                const float v = acc[rt][tt][r] + bb;
                if (proj == 0) {
                    qws[(size_t)row * 128 + col] = (__bf16)(v * QSCALE);
                } else if (proj == 1) {
                    kws[(size_t)row * 128 + col] = (__bf16)v;
                } else {
                    const int b_ = row >> 12;
                    const int s_ = row & 4095;
                    vT[(size_t)b_ * 524288 + (size_t)col * 4096 + s_] = (__bf16)v;
                }
            }
        }
    }
}

// ---------------- Kernel 2: causal flash attention ----------------
// Swapped QK^T (S^T = K.Q^T): lane owns ONE q-column -> softmax in-register.
// No LDS, no barriers; each wave = one (16-row strip, KV segment) task.
// Partial slot: 2080 f32 = [16][128] O + [16] m + [16] l.
__global__ __launch_bounds__(256) void attn(const __bf16* __restrict__ qws,
                                            const __bf16* __restrict__ kws,
                                            const __bf16* __restrict__ vT,
                                            float* __restrict__ part,
                                            float* __restrict__ out,
                                            int NSEG, int SEG, int direct) {
    const int w  = threadIdx.x >> 6;
    const int l  = threadIdx.x & 63;
    const int lo = l & 15;
    const int hi = l >> 4;

    const int task = blockIdx.x * 4 + w;
    const int sidx = task / NSEG;           // 0..1023 strip
    const int seg  = task - sidx * NSEG;
    const int batch = sidx & 3;
    const int m     = 255 - (sidx >> 2);    // longest strips first
    const int q0    = m * 16;
    const int extent = q0 + 16;

    const int kv_start = seg * SEG;
    if (kv_start >= extent) return;
    const int kv_end = min(kv_start + SEG, extent);
    const int t0 = kv_start >> 6;
    const int t1 = (kv_end + 63) >> 6;

    // Q fragments (validated layout: lane -> row lo, k = hi*8+j)
    const size_t qoff = (size_t)(batch * 4096 + q0 + lo) * 128 + hi * 8;
    bf16x8 qf[4];
#pragma unroll
    for (int dc = 0; dc < 4; ++dc)
        qf[dc] = *reinterpret_cast<const bf16x8*>(qws + qoff + dc * 32);

    const __bf16* kb = kws + (size_t)batch * 524288;
    const __bf16* vb = vT  + (size_t)batch * 524288;

    f32x4 o[8];
#pragma unroll
    for (int dt = 0; dt < 8; ++dt) o[dt] = (f32x4){0.f, 0.f, 0.f, 0.f};
    float mr = -__builtin_inff();
    float lr = 0.f;

    for (int t = t0; t < t1; ++t) {
        const int kvb = t * 64;

        // ---- S^T[kv][q] = K . Q^T : lane owns q-column lo ----
        f32x4 s[4];
#pragma unroll
        for (int ct = 0; ct < 4; ++ct) s[ct] = (f32x4){0.f, 0.f, 0.f, 0.f};
#pragma unroll
        for (int ct = 0; ct < 4; ++ct) {
#pragma unroll
            for (int dc = 0; dc < 4; ++dc) {
                bf16x8 kf = *reinterpret_cast<const bf16x8*>(
                    kb + (size_t)(kvb + ct * 16 + lo) * 128 + dc * 32 + hi * 8);
                s[ct] = __builtin_amdgcn_mfma_f32_16x16x32_bf16(kf, qf[dc], s[ct], 0, 0, 0);
            }
        }

        // ---- V chunk-0 loads issued early (fly under softmax) ----
        bf16x8 vf0[8];
#pragma unroll
        for (int dt = 0; dt < 8; ++dt)
            vf0[dt] = *reinterpret_cast<const bf16x8*>(
                vb + (size_t)(dt * 16 + lo) * 4096 + kvb + hi * 8);

        // ---- causal mask (diagonal tile only): kv = kvb+ct*16+hi*4+r, q = q0+lo
        if (kvb + 63 > q0) {
#pragma unroll
            for (int ct = 0; ct < 4; ++ct) {
#pragma unroll
                for (int r = 0; r < 4; ++r) {
                    if (kvb + ct * 16 + hi * 4 + r > q0 + lo)
                        s[ct][r] = -__builtin_inff();
                }
            }
        }

        // ---- in-register softmax (per q-column; 2 shfl total for max) ----
        float mloc = s[0][0];
#pragma unroll
        for (int ct = 0; ct < 4; ++ct)
#pragma unroll
            for (int r = 0; r < 4; ++r) mloc = fmaxf(mloc, s[ct][r]);
        mloc = fmaxf(mloc, __shfl_xor(mloc, 16));
        mloc = fmaxf(mloc, __shfl_xor(mloc, 32));

        const float mn = fmaxf(mr, mloc);
        const float alpha = exp2f(mr - mn);
        mr = mn;

        float rs = 0.f;
#pragma unroll
        for (int ct = 0; ct < 4; ++ct) {
#pragma unroll
            for (int r = 0; r < 4; ++r) {
                const float pv = exp2f(s[ct][r] - mn);
                s[ct][r] = pv;
                rs += pv;
            }
        }
        rs += __shfl_xor(rs, 16);
        rs += __shfl_xor(rs, 32);
        lr = lr * alpha + rs;

        // ---- O rescale (alpha relocated q-col -> q-row via 4 shfl) ----
        float ao[4];
#pragma unroll
        for (int r = 0; r < 4; ++r) ao[r] = __shfl(alpha, hi * 4 + r);
#pragma unroll
        for (int dt = 0; dt < 8; ++dt)
#pragma unroll
            for (int r = 0; r < 4; ++r) o[dt][r] *= ao[r];

        // ---- P -> bf16 A-fragments via packed bpermute exchange ----
        int pk0[2], pk1[2], pk2[2], pk3[2];
        pk0[0] = pack2(s[0][0], s[0][1]); pk0[1] = pack2(s[0][2], s[0][3]);
        pk1[0] = pack2(s[1][0], s[1][1]); pk1[1] = pack2(s[1][2], s[1][3]);
        pk2[0] = pack2(s[2][0], s[2][1]); pk2[1] = pack2(s[2][2], s[2][3]);
        pk3[0] = pack2(s[3][0], s[3][1]); pk3[1] = pack2(s[3][2], s[3][3]);

        const int src1 = lo + ((hi & 1) << 5);   // lane (lo, 2*(hi&1))
        const int src2 = src1 + 16;              // lane (lo, 2*(hi&1)+1)
        const bool usel = hi >= 2;

        union { int u[4]; bf16x8 v; } pa0, pa1;
        {
            int a0 = __shfl(pk0[0], src1), a1 = __shfl(pk0[1], src1);
            int b0 = __shfl(pk1[0], src1), b1 = __shfl(pk1[1], src1);
            int a2 = __shfl(pk0[0], src2), a3 = __shfl(pk0[1], src2);
            int b2 = __shfl(pk1[0], src2), b3 = __shfl(pk1[1], src2);
            pa0.u[0] = usel ? b0 : a0; pa0.u[1] = usel ? b1 : a1;
            pa0.u[2] = usel ? b2 : a2; pa0.u[3] = usel ? b3 : a3;
        }
        {
            int a0 = __shfl(pk2[0], src1), a1 = __shfl(pk2[1], src1);
            int b0 = __shfl(pk3[0], src1), b1 = __shfl(pk3[1], src1);
            int a2 = __shfl(pk2[0], src2), a3 = __shfl(pk2[1], src2);
            int b2 = __shfl(pk3[0], src2), b3 = __shfl(pk3[1], src2);
            pa1.u[0] = usel ? b0 : a0; pa1.u[1] = usel ? b1 : a1;
            pa1.u[2] = usel ? b2 : a2; pa1.u[3] = usel ? b3 : a3;
        }

        // ---- V chunk-1 loads (hide under chunk-0 MFMA) ----
        bf16x8 vf1[8];
#pragma unroll
        for (int dt = 0; dt < 8; ++dt)
            vf1[dt] = *reinterpret_cast<const bf16x8*>(
                vb + (size_t)(dt * 16 + lo) * 4096 + kvb + 32 + hi * 8);

        // ---- O += P . V ----
#pragma unroll
        for (int dt = 0; dt < 8; ++dt)
            o[dt] = __builtin_amdgcn_mfma_f32_16x16x32_bf16(pa0.v, vf0[dt], o[dt], 0, 0, 0);
#pragma unroll
        for (int dt = 0; dt < 8; ++dt)
            o[dt] = __builtin_amdgcn_mfma_f32_16x16x32_bf16(pa1.v, vf1[dt], o[dt], 0, 0, 0);
    }

    // ---- relocate state q-col -> q-row, write out ----
    float lro[4], mro[4];
#pragma unroll
    for (int r = 0; r < 4; ++r) {
        lro[r] = __shfl(lr, hi * 4 + r);
        mro[r] = __shfl(mr, hi * 4 + r);
    }

    if (direct) {
#pragma unroll
        for (int dt = 0; dt < 8; ++dt)
#pragma unroll
            for (int r = 0; r < 4; ++r) {
                const size_t row = (size_t)(batch * 4096 + q0 + hi * 4 + r);
                out[row * 128 + dt * 16 + lo] = o[dt][r] / lro[r];
            }
    } else {
        float* slot = part + ((size_t)sidx * NSEG + seg) * 2080;
#pragma unroll
        for (int dt = 0; dt < 8; ++dt)
#pragma unroll
            for (int r = 0; r < 4; ++r)
                slot[(hi * 4 + r) * 128 + dt * 16 + lo] = o[dt][r];
        if (lo == 0) {
#pragma unroll
            for (int r = 0; r < 4; ++r) {
                slot[2048 + hi * 4 + r] = mro[r];
                slot[2064 + hi * 4 + r] = lro[r];
            }
        }
    }
}

// ---------------- Kernel 3: combine KV-split partials ----------------
__global__ __launch_bounds__(256) void combine(const float* __restrict__ part,
                                               float* __restrict__ out,
                                               int NSEG, int SEG) {
    const int strip = blockIdx.x;
    const int batch = strip & 3;
    const int m     = 255 - (strip >> 2);
    const int limit = m * 16 + 16;
    const int nseg  = min(NSEG, (limit + SEG - 1) / SEG);

    const int r  = threadIdx.x >> 4;
    const int c0 = (threadIdx.x & 15) * 8;
    const float* base = part + (size_t)strip * NSEG * 2080;

    float mj[8];
    float M = -__builtin_inff();
#pragma unroll 8
    for (int j = 0; j < 8; ++j) {
        if (j < nseg) {
            mj[j] = base[j * 2080 + 2048 + r];
            M = fmaxf(M, mj[j]);
        }
    }
    float wj[8];
    float L = 0.f;
#pragma unroll 8
    for (int j = 0; j < 8; ++j) {
        if (j < nseg) {
            wj[j] = exp2f(mj[j] - M);
            L += base[j * 2080 + 2064 + r] * wj[j];
        }
    }

    float a0=0,a1=0,a2=0,a3=0,a4=0,a5=0,a6=0,a7=0;
#pragma unroll 8
    for (int j = 0; j < 8; ++j) {
        if (j < nseg) {
            const float4* p4 = reinterpret_cast<const float4*>(base + j * 2080 + r * 128 + c0);
            float4 xx = p4[0], yy = p4[1];
            const float wgt = wj[j];
            a0 += xx.x*wgt; a1 += xx.y*wgt; a2 += xx.z*wgt; a3 += xx.w*wgt;
            a4 += yy.x*wgt; a5 += yy.y*wgt; a6 += yy.z*wgt; a7 += yy.w*wgt;
        }
    }
    const float inv = 1.f / L;
    float* op = out + ((size_t)(batch * 4096 + m * 16 + r)) * 128 + c0;
    float4* o4 = reinterpret_cast<float4*>(op);
    o4[0] = (float4){a0*inv, a1*inv, a2*inv, a3*inv};
    o4[1] = (float4){a4*inv, a5*inv, a6*inv, a7*inv};
}

// ---------------- Launch ----------------
extern "C" void kernel_launch(void* const* d_in, const int* in_sizes, int n_in,
                              void* d_out, int out_size, void* d_ws, size_t ws_size,
                              hipStream_t stream) {
    const float* x  = (const float*)d_in[0];
    const float* Wk = (const float*)d_in[1];
    const float* bk = (const float*)d_in[2];
    const float* Wq = (const float*)d_in[3];
    const float* bq = (const float*)d_in[4];
    const float* Wv = (const float*)d_in[5];
    const float* bv = (const float*)d_in[6];
    float* out = (float*)d_out;

    char* ws = (char*)d_ws;
    __bf16* Wt  = (__bf16*)ws;                                // 786432 B
    __bf16* qws = (__bf16*)(ws + 786432);                     // 4 MB
    __bf16* kws = (__bf16*)(ws + 786432 + 4194304);           // 4 MB
    __bf16* vT  = (__bf16*)(ws + 786432 + 2 * 4194304);       // 4 MB
    const size_t base = 786432 + 3 * 4194304;                 // 13369344 B

    // largest KV-split that fits: per NSEG unit = 1024 strips * 2080 * 4 B
    const size_t per_seg = 1024ull * 2080 * 4;
    int NSEG = 1;
    for (int cand = 8; cand >= 2; cand >>= 1) {
        if (base + (size_t)cand * per_seg <= ws_size) { NSEG = cand; break; }
    }
    float* part = (float*)(ws + base);

    prep_w<<<1536, 256, 0, stream>>>(Wq, Wk, Wv, Wt);
    qkv_gemm<<<512, 512, 0, stream>>>(x, Wt, bq, bk, bv, qws, kws, vT);

    if (NSEG >= 2) {
        const int SEG = 4096 / NSEG;
        attn<<<256 * NSEG, 256, 0, stream>>>(qws, kws, vT, part, out, NSEG, SEG, 0);
        combine<<<1024, 256, 0, stream>>>(part, out, NSEG, SEG);
    } else {
        attn<<<256, 256, 0, stream>>>(qws, kws, vT, nullptr, out, 1, 4096, 1);
    }
}

// Round 5
// 137.202 us; speedup vs baseline: 3.4640x; 1.9373x over previous
//
#include <hip/hip_runtime.h>
#include <hip/hip_bf16.h>

typedef __attribute__((ext_vector_type(8))) __bf16 bf16x8;
typedef __attribute__((ext_vector_type(4))) float f32x4;

// 1/sqrt(128) * log2(e): Q pre-scaled so softmax exponents are base-2
#define QSCALE (0.08838834764831845f * 1.4426950408889634f)

static __device__ __forceinline__ int pack2(float a, float b) {
    union { __bf16 h[2]; int u; } x;
    x.h[0] = (__bf16)a; x.h[1] = (__bf16)b;
    return x.u;
}

// ---------------- Kernel 0: transpose + cast weights ----------------
__global__ __launch_bounds__(256) void prep_w(const float* __restrict__ Wq,
                                              const float* __restrict__ Wk,
                                              const float* __restrict__ Wv,
                                              __bf16* __restrict__ Wt) {
    int idx = blockIdx.x * 256 + threadIdx.x;
    int p   = idx >> 17;
    int rem = idx & 131071;
    int c   = rem >> 10;
    int k   = rem & 1023;
    const float* W = (p == 0) ? Wq : ((p == 1) ? Wk : Wv);
    Wt[idx] = (__bf16)W[k * 128 + c];
}

// ---------------- Kernel 1: fused QKV projection ----------------
// 512 blocks x 512 thr (8 waves). Block stages x[32][1024] -> LDS bf16
// (XOR-swizzled 16B units). Wave w: col-tiles w*3..w*3+2, both 16-row tiles.
__global__ __launch_bounds__(512) void qkv_gemm(const float* __restrict__ x,
                                                const __bf16* __restrict__ Wt,
                                                const float* __restrict__ bq,
                                                const float* __restrict__ bk,
                                                const float* __restrict__ bv,
                                                __bf16* __restrict__ qws,
                                                __bf16* __restrict__ kws,
                                                __bf16* __restrict__ vT) {
    __shared__ __align__(16) __bf16 xb[32 * 1024];   // 64 KB

    const int tid = threadIdx.x;
    const int w   = tid >> 6;
    const int l   = tid & 63;
    const int lo  = l & 15;
    const int hi  = l >> 4;
    const int r0  = blockIdx.x * 32;

#pragma unroll
    for (int i = 0; i < 8; ++i) {
        const int ul  = i * 512 + tid;
        const int row = ul >> 7;
        const int u   = ul & 127;
        const float4* src = reinterpret_cast<const float4*>(
            x + (size_t)(r0 + row) * 1024 + u * 8);
        float4 f0 = src[0], f1 = src[1];
        bf16x8 v;
        v[0]=(__bf16)f0.x; v[1]=(__bf16)f0.y; v[2]=(__bf16)f0.z; v[3]=(__bf16)f0.w;
        v[4]=(__bf16)f1.x; v[5]=(__bf16)f1.y; v[6]=(__bf16)f1.z; v[7]=(__bf16)f1.w;
        *reinterpret_cast<bf16x8*>(&xb[row * 1024 + ((u ^ (row & 7)) * 8)]) = v;
    }
    __syncthreads();

    f32x4 acc[2][3];
#pragma unroll
    for (int rt = 0; rt < 2; ++rt)
#pragma unroll
        for (int tt = 0; tt < 3; ++tt) acc[rt][tt] = (f32x4){0.f, 0.f, 0.f, 0.f};

    const int tbase = w * 3;
#pragma unroll 4
    for (int kc = 0; kc < 32; ++kc) {
        const int usw = ((kc * 4 + hi) ^ (lo & 7)) * 8;
        bf16x8 a0 = *reinterpret_cast<const bf16x8*>(&xb[lo * 1024 + usw]);
        bf16x8 a1 = *reinterpret_cast<const bf16x8*>(&xb[(16 + lo) * 1024 + usw]);
#pragma unroll
        for (int tt = 0; tt < 3; ++tt) {
            const int t = tbase + tt;
            bf16x8 b = *reinterpret_cast<const bf16x8*>(
                Wt + (t >> 3) * 131072 + (t & 7) * 16384 + lo * 1024 + kc * 32 + hi * 8);
            acc[0][tt] = __builtin_amdgcn_mfma_f32_16x16x32_bf16(a0, b, acc[0][tt], 0, 0, 0);
            acc[1][tt] = __builtin_amdgcn_mfma_f32_16x16x32_bf16(a1, b, acc[1][tt], 0, 0, 0);
        }
    }

#pragma unroll
    for (int tt = 0; tt < 3; ++tt) {
        const int t    = tbase + tt;
        const int proj = t >> 3;
        const int col  = (t & 7) * 16 + lo;
        const float* bias = (proj == 0) ? bq : ((proj == 1) ? bk : bv);
        const float bb = bias[col];
#pragma unroll
        for (int rt = 0; rt < 2; ++rt) {
#pragma unroll
            for (int r = 0; r < 4; ++r) {
                const int row = r0 + rt * 16 + hi * 4 + r;
                const float v = acc[rt][tt][r] + bb;
                if (proj == 0) {
                    qws[(size_t)row * 128 + col] = (__bf16)(v * QSCALE);
                } else if (proj == 1) {
                    kws[(size_t)row * 128 + col] = (__bf16)v;
                } else {
                    const int b_ = row >> 12;
                    const int s_ = row & 4095;
                    vT[(size_t)b_ * 524288 + (size_t)col * 4096 + s_] = (__bf16)v;
                }
            }
        }
    }
}

// ---------------- Kernel 2: causal flash attention ----------------
// 8 waves/block, 128 Q rows/block (wave w: rows q0+16w..+15).
// K[64][128] + V^T[128][64] staged in LDS per tile, XOR-swizzled, shared by
// all waves; reg-staged prefetch of next tile. Swapped QK^T -> in-register
// softmax; P via wave-private LDS (no barrier). KV-split NSEG segments.
// Partial slot: 16640 f32 = [128][128] O + [128] m + [128] l.
__global__ __launch_bounds__(512, 4) void attn(const __bf16* __restrict__ qws,
                                               const __bf16* __restrict__ kws,
                                               const __bf16* __restrict__ vT,
                                               float* __restrict__ part,
                                               float* __restrict__ out,
                                               int NSEG, int SEG, int direct) {
    __shared__ __align__(16) __bf16 K_lds[64 * 128];    // 16 KB
    __shared__ __align__(16) __bf16 V_lds[128 * 64];    // 16 KB (V^T tile)
    __shared__ __align__(16) __bf16 p_lds[8][16 * 80];  // 20 KB wave-private

    const int tid = threadIdx.x;
    const int w   = tid >> 6;
    const int l   = tid & 63;
    const int lo  = l & 15;
    const int hi  = l >> 4;

    const int task = blockIdx.x;
    const int sidx = task / NSEG;            // 0..127 strip (128 rows)
    const int seg  = task - sidx * NSEG;
    const int batch = sidx & 3;
    const int mblk  = 31 - (sidx >> 2);      // longest strips first
    const int q0    = mblk * 128;
    const int extent = q0 + 128;             // causal KV extent (128-aligned)

    const int kv_start = seg * SEG;
    if (kv_start >= extent) return;
    const int kv_end = min(kv_start + SEG, extent);
    const int t0 = kv_start >> 6;
    const int t1 = (kv_end + 63) >> 6;

    const int rw = q0 + w * 16;              // wave's first q row

    // staging decomposition: thread covers 2 K-units + 2 V-units (16B each)
    const int tKrow = tid >> 3;              // 0..63
    const int tKu   = (tid & 7) * 2;         // even unit in 0..14
    const int tVrow = tid >> 2;              // 0..127
    const int tVu   = (tid & 3) * 2;         // even unit in 0..6

    const __bf16* kb = kws + (size_t)batch * 524288;
    const __bf16* vb = vT  + (size_t)batch * 524288;

    // Q fragments
    const size_t qoff = (size_t)(batch * 4096 + rw + lo) * 128 + hi * 8;
    bf16x8 qf[4];
#pragma unroll
    for (int dc = 0; dc < 4; ++dc)
        qf[dc] = *reinterpret_cast<const bf16x8*>(qws + qoff + dc * 32);

    // ---- prologue: stage tile t0 ----
    {
        const int kvb = t0 * 64;
        bf16x8 k0 = *reinterpret_cast<const bf16x8*>(kb + (size_t)(kvb + tKrow) * 128 + tKu * 8);
        bf16x8 k1 = *reinterpret_cast<const bf16x8*>(kb + (size_t)(kvb + tKrow) * 128 + tKu * 8 + 8);
        bf16x8 v0 = *reinterpret_cast<const bf16x8*>(vb + (size_t)tVrow * 4096 + kvb + tVu * 8);
        bf16x8 v1 = *reinterpret_cast<const bf16x8*>(vb + (size_t)tVrow * 4096 + kvb + tVu * 8 + 8);
        *reinterpret_cast<bf16x8*>(&K_lds[tKrow * 128 + ((tKu       ^ (tKrow & 7)) * 8)]) = k0;
        *reinterpret_cast<bf16x8*>(&K_lds[tKrow * 128 + (((tKu + 1) ^ (tKrow & 7)) * 8)]) = k1;
        *reinterpret_cast<bf16x8*>(&V_lds[tVrow * 64  + ((tVu       ^ (tVrow & 7)) * 8)]) = v0;
        *reinterpret_cast<bf16x8*>(&V_lds[tVrow * 64  + (((tVu + 1) ^ (tVrow & 7)) * 8)]) = v1;
        __syncthreads();
    }

    f32x4 o[8];
#pragma unroll
    for (int dt = 0; dt < 8; ++dt) o[dt] = (f32x4){0.f, 0.f, 0.f, 0.f};
    float mr = -__builtin_inff();
    float lr = 0.f;

    for (int t = t0; t < t1; ++t) {
        const int kvb = t * 64;
        const bool pfetch = (t + 1 < t1);

        // ---- issue next tile's global loads (hide under compute) ----
        bf16x8 kr0, kr1, vr0, vr1;
        if (pfetch) {
            const int kvn = kvb + 64;
            kr0 = *reinterpret_cast<const bf16x8*>(kb + (size_t)(kvn + tKrow) * 128 + tKu * 8);
            kr1 = *reinterpret_cast<const bf16x8*>(kb + (size_t)(kvn + tKrow) * 128 + tKu * 8 + 8);
            vr0 = *reinterpret_cast<const bf16x8*>(vb + (size_t)tVrow * 4096 + kvn + tVu * 8);
            vr1 = *reinterpret_cast<const bf16x8*>(vb + (size_t)tVrow * 4096 + kvn + tVu * 8 + 8);
        }

        // ---- per-wave compute (skip if this wave is fully above diagonal) ----
        if (kvb <= rw + 15) {
            // S^T = K . Q^T : lane owns q-column lo
            f32x4 s[4];
#pragma unroll
            for (int ct = 0; ct < 4; ++ct) s[ct] = (f32x4){0.f, 0.f, 0.f, 0.f};
            const int sw = lo & 7;
#pragma unroll
            for (int ct = 0; ct < 4; ++ct) {
                const int rbase = (ct * 16 + lo) * 128;
#pragma unroll
                for (int dc = 0; dc < 4; ++dc) {
                    bf16x8 kf = *reinterpret_cast<const bf16x8*>(
                        &K_lds[rbase + (((dc * 4 + hi) ^ sw) << 3)]);
                    s[ct] = __builtin_amdgcn_mfma_f32_16x16x32_bf16(kf, qf[dc], s[ct], 0, 0, 0);
                }
            }

            // causal mask (diagonal region): kv = kvb+ct*16+hi*4+r, q = rw+lo
            if (kvb + 63 > rw) {
#pragma unroll
                for (int ct = 0; ct < 4; ++ct)
#pragma unroll
                    for (int r = 0; r < 4; ++r)
                        if (kvb + ct * 16 + hi * 4 + r > rw + lo)
                            s[ct][r] = -__builtin_inff();
            }

            // in-register softmax (per q-column)
            float mloc = s[0][0];
#pragma unroll
            for (int ct = 0; ct < 4; ++ct)
#pragma unroll
                for (int r = 0; r < 4; ++r) mloc = fmaxf(mloc, s[ct][r]);
            mloc = fmaxf(mloc, __shfl_xor(mloc, 16));
            mloc = fmaxf(mloc, __shfl_xor(mloc, 32));

            const float mn = fmaxf(mr, mloc);
            const float alpha = exp2f(mr - mn);
            mr = mn;

            float rs = 0.f;
#pragma unroll
            for (int ct = 0; ct < 4; ++ct) {
#pragma unroll
                for (int r = 0; r < 4; ++r) {
                    const float pv = exp2f(s[ct][r] - mn);
                    s[ct][r] = pv;
                    rs += pv;
                }
            }
            rs += __shfl_xor(rs, 16);
            rs += __shfl_xor(rs, 32);
            lr = lr * alpha + rs;

            float ao[4];
#pragma unroll
            for (int r = 0; r < 4; ++r) ao[r] = __shfl(alpha, hi * 4 + r);
#pragma unroll
            for (int dt = 0; dt < 8; ++dt)
#pragma unroll
                for (int r = 0; r < 4; ++r) o[dt][r] *= ao[r];

            // P -> wave-private LDS (P[q=lo][kv]), then A-fragments
#pragma unroll
            for (int ct = 0; ct < 4; ++ct) {
                int2 pw;
                pw.x = pack2(s[ct][0], s[ct][1]);
                pw.y = pack2(s[ct][2], s[ct][3]);
                *reinterpret_cast<int2*>(&p_lds[w][lo * 80 + ct * 16 + hi * 4]) = pw;
            }
            bf16x8 pf0 = *reinterpret_cast<const bf16x8*>(&p_lds[w][lo * 80 + hi * 8]);
            bf16x8 pf1 = *reinterpret_cast<const bf16x8*>(&p_lds[w][lo * 80 + 32 + hi * 8]);

            // O += P . V  (V^T fragments from LDS)
#pragma unroll
            for (int dt = 0; dt < 8; ++dt) {
                const int vbase = (dt * 16 + lo) * 64;
                bf16x8 vf0 = *reinterpret_cast<const bf16x8*>(
                    &V_lds[vbase + ((hi ^ sw) << 3)]);
                o[dt] = __builtin_amdgcn_mfma_f32_16x16x32_bf16(pf0, vf0, o[dt], 0, 0, 0);
                bf16x8 vf1 = *reinterpret_cast<const bf16x8*>(
                    &V_lds[vbase + (((4 + hi) ^ sw) << 3)]);
                o[dt] = __builtin_amdgcn_mfma_f32_16x16x32_bf16(pf1, vf1, o[dt], 0, 0, 0);
            }
        }

        // ---- commit next tile to LDS ----
        if (pfetch) {
            __syncthreads();   // all waves done reading current tile
            *reinterpret_cast<bf16x8*>(&K_lds[tKrow * 128 + ((tKu       ^ (tKrow & 7)) * 8)]) = kr0;
            *reinterpret_cast<bf16x8*>(&K_lds[tKrow * 128 + (((tKu + 1) ^ (tKrow & 7)) * 8)]) = kr1;
            *reinterpret_cast<bf16x8*>(&V_lds[tVrow * 64  + ((tVu       ^ (tVrow & 7)) * 8)]) = vr0;
            *reinterpret_cast<bf16x8*>(&V_lds[tVrow * 64  + (((tVu + 1) ^ (tVrow & 7)) * 8)]) = vr1;
            __syncthreads();   // writes visible
        }
    }

    // ---- relocate state q-col -> q-row, write out ----
    float lro[4], mro[4];
#pragma unroll
    for (int r = 0; r < 4; ++r) {
        lro[r] = __shfl(lr, hi * 4 + r);
        mro[r] = __shfl(mr, hi * 4 + r);
    }

    if (direct) {
#pragma unroll
        for (int dt = 0; dt < 8; ++dt)
#pragma unroll
            for (int r = 0; r < 4; ++r) {
                const size_t row = (size_t)(batch * 4096 + rw + hi * 4 + r);
                out[row * 128 + dt * 16 + lo] = o[dt][r] / lro[r];
            }
    } else {
        float* slot = part + ((size_t)sidx * NSEG + seg) * 16640;
#pragma unroll
        for (int dt = 0; dt < 8; ++dt)
#pragma unroll
            for (int r = 0; r < 4; ++r)
                slot[(w * 16 + hi * 4 + r) * 128 + dt * 16 + lo] = o[dt][r];
        if (lo == 0) {
#pragma unroll
            for (int r = 0; r < 4; ++r) {
                slot[16384 + w * 16 + hi * 4 + r] = mro[r];
                slot[16512 + w * 16 + hi * 4 + r] = lro[r];
            }
        }
    }
}

// ---------------- Kernel 3: combine KV-split partials ----------------
// 1024 blocks x 256 thr: block = (strip 0..127, 16-row group 0..7).
__global__ __launch_bounds__(256) void combine(const float* __restrict__ part,
                                               float* __restrict__ out,
                                               int NSEG, int SEG) {
    const int strip = blockIdx.x >> 3;
    const int rg    = blockIdx.x & 7;
    const int batch = strip & 3;
    const int mblk  = 31 - (strip >> 2);
    const int extent = mblk * 128 + 128;
    const int nseg  = min(NSEG, (extent + SEG - 1) / SEG);

    const int rl = rg * 16 + (threadIdx.x >> 4);   // 0..127
    const int c0 = (threadIdx.x & 15) * 8;
    const float* base = part + (size_t)strip * NSEG * 16640;

    float mj[8];
    float M = -__builtin_inff();
#pragma unroll 8
    for (int j = 0; j < 8; ++j) {
        if (j < nseg) {
            mj[j] = base[j * 16640 + 16384 + rl];
            M = fmaxf(M, mj[j]);
        }
    }
    float wj[8];
    float L = 0.f;
#pragma unroll 8
    for (int j = 0; j < 8; ++j) {
        if (j < nseg) {
            wj[j] = exp2f(mj[j] - M);
            L += base[j * 16640 + 16512 + rl] * wj[j];
        }
    }

    float a0=0,a1=0,a2=0,a3=0,a4=0,a5=0,a6=0,a7=0;
#pragma unroll 8
    for (int j = 0; j < 8; ++j) {
        if (j < nseg) {
            const float4* p4 = reinterpret_cast<const float4*>(base + j * 16640 + rl * 128 + c0);
            float4 xx = p4[0], yy = p4[1];
            const float wgt = wj[j];
            a0 += xx.x*wgt; a1 += xx.y*wgt; a2 += xx.z*wgt; a3 += xx.w*wgt;
            a4 += yy.x*wgt; a5 += yy.y*wgt; a6 += yy.z*wgt; a7 += yy.w*wgt;
        }
    }
    const float inv = 1.f / L;
    float* op = out + ((size_t)(batch * 4096 + mblk * 128 + rl)) * 128 + c0;
    float4* o4 = reinterpret_cast<float4*>(op);
    o4[0] = (float4){a0*inv, a1*inv, a2*inv, a3*inv};
    o4[1] = (float4){a4*inv, a5*inv, a6*inv, a7*inv};
}

// ---------------- Launch ----------------
extern "C" void kernel_launch(void* const* d_in, const int* in_sizes, int n_in,
                              void* d_out, int out_size, void* d_ws, size_t ws_size,
                              hipStream_t stream) {
    const float* x  = (const float*)d_in[0];
    const float* Wk = (const float*)d_in[1];
    const float* bk = (const float*)d_in[2];
    const float* Wq = (const float*)d_in[3];
    const float* bq = (const float*)d_in[4];
    const float* Wv = (const float*)d_in[5];
    const float* bv = (const float*)d_in[6];
    float* out = (float*)d_out;

    char* ws = (char*)d_ws;
    __bf16* Wt  = (__bf16*)ws;                                // 786432 B
    __bf16* qws = (__bf16*)(ws + 786432);                     // 4 MB
    __bf16* kws = (__bf16*)(ws + 786432 + 4194304);           // 4 MB
    __bf16* vT  = (__bf16*)(ws + 786432 + 2 * 4194304);       // 4 MB
    const size_t base = 786432 + 3 * 4194304;                 // 13369344 B

    // largest KV-split that fits: per NSEG unit = 128 strips * 16640 * 4 B
    const size_t per_seg = 128ull * 16640 * 4;
    int NSEG = 1;
    for (int cand = 8; cand >= 2; cand >>= 1) {
        if (base + (size_t)cand * per_seg <= ws_size) { NSEG = cand; break; }
    }
    float* part = (float*)(ws + base);

    prep_w<<<1536, 256, 0, stream>>>(Wq, Wk, Wv, Wt);
    qkv_gemm<<<512, 512, 0, stream>>>(x, Wt, bq, bk, bv, qws, kws, vT);

    if (NSEG >= 2) {
        const int SEG = 4096 / NSEG;
        attn<<<128 * NSEG, 512, 0, stream>>>(qws, kws, vT, part, out, NSEG, SEG, 0);
        combine<<<1024, 256, 0, stream>>>(part, out, NSEG, SEG);
    } else {
        attn<<<128, 512, 0, stream>>>(qws, kws, vT, nullptr, out, 1, 4096, 1);
    }
}